// Round 13
// baseline (2714.169 us; speedup 1.0000x reference)
//
#include <hip/hip_runtime.h>
#include <hip/hip_bf16.h>

#define DD 128            // codebook dim

typedef float f2v __attribute__((ext_vector_type(2)));

__global__ void plant_diag(float val, float* out) {
    if (threadIdx.x == 0 && blockIdx.x == 0) out[0] = val;
}

__global__ void zero_acc(double* acc) {
    if (threadIdx.x == 0 && blockIdx.x == 0) { acc[0] = 0.0; acc[1] = 0.0; }
}

// ---------------- silu mimicking np: x * (1/(1+exp(-x))), each op f32-rounded ----------------
__device__ __forceinline__ float silu_np(float x) {
    float e = (float)exp(-(double)x);   // correctly-rounded f32 exp
    float u = 1.0f + e;
    float v = 1.0f / u;
    return x * v;
}

// ---------------- gemm88: C = act(A@W + b) — 128x128 tile, 8x8/thread, EXACT chains --------
// Round-13: doubles work per barrier window (GEMM measured latency/barrier-bound: VALUBusy
// 25% with neither pipe saturated) and improves LDS-read:FMA ratio 2.25->1.5. Per thread:
// 8 rows (ty+16i) x two 4-col groups (4tx and 64+4tx) — both LDS read patterns keep the
// proven conflict-free 4-float spacing. A register-prefetched (ra[16], HBM overlap); W
// staged TRANSIENTLY between barriers (round-5 de-spill pattern; live ~130 VGPR).
// Chain per output unchanged: k = 32p + 4kq + q ascending, zero-filled OOB => bit-identical.
template <bool SILU>
__global__ __launch_bounds__(256) void gemm88(const float* __restrict__ A,
                                              const float* __restrict__ W,
                                              const float* __restrict__ bias,
                                              float* __restrict__ C,
                                              int M, int N, int K) {
    __shared__ __align__(16) float As[128][36];   // 18432 B
    __shared__ __align__(16) float Ws[32][132];   // 16896 B
    const int t = threadIdx.x;
    const int tx = t & 15, ty = t >> 4;       // tx: col quads, ty: 8 rows (ty+16i)
    const int bm = blockIdx.y * 128, bn = blockIdx.x * 128;

    float acc[8][8];
#pragma unroll
    for (int i = 0; i < 8; ++i)
#pragma unroll
        for (int j = 0; j < 8; ++j) acc[i][j] = 0.0f;

    const int nPanels = (K + 31) / 32;
    float ra[16];

    {
        const int k0 = 0;
#pragma unroll
        for (int it = 0; it < 16; ++it) {     // A-panel: 128 x 32
            int e = t + 256 * it;
            int m = e >> 5, kk = e & 31;
            int mm = bm + m; if (mm >= M) mm = M - 1;
            int kc = k0 + kk;
            ra[it] = (kc < K) ? A[(size_t)mm * K + kc] : 0.0f;
        }
    }

    for (int p = 0; p < nPanels; ++p) {
        __syncthreads();
#pragma unroll
        for (int it = 0; it < 16; ++it) {
            int e = t + 256 * it;
            As[e >> 5][e & 31] = ra[it];
        }
        // stage W-panel 32x128 transiently (global->reg->LDS, registers recycled)
        {
            const int kp0 = 32 * p;
#pragma unroll
            for (int it = 0; it < 16; ++it) {
                int e = t + 256 * it;
                int r = e >> 7, c = e & 127;
                int n = bn + c;
                int kr = kp0 + r;
                float wv = (kr < K && n < N) ? W[(size_t)kr * N + n] : 0.0f;
                Ws[r][c] = wv;
            }
        }
        __syncthreads();

        if (p + 1 < nPanels) {                // prefetch next A panel (overlaps compute)
            const int k0 = (p + 1) * 32;
#pragma unroll
            for (int it = 0; it < 16; ++it) {
                int e = t + 256 * it;
                int m = e >> 5, kk = e & 31;
                int mm = bm + m; if (mm >= M) mm = M - 1;
                int kc = k0 + kk;
                ra[it] = (kc < K) ? A[(size_t)mm * K + kc] : 0.0f;
            }
        }

#pragma unroll
        for (int kq = 0; kq < 8; ++kq) {
            float4 a4[8], wA[4], wB[4];
#pragma unroll
            for (int i = 0; i < 8; ++i)
                a4[i] = *(const float4*)&As[ty + 16 * i][4 * kq];
#pragma unroll
            for (int q = 0; q < 4; ++q) {
                wA[q] = *(const float4*)&Ws[4 * kq + q][4 * tx];
                wB[q] = *(const float4*)&Ws[4 * kq + q][64 + 4 * tx];
            }
#pragma unroll
            for (int q = 0; q < 4; ++q) {
                const float w0[4] = {wA[q].x, wA[q].y, wA[q].z, wA[q].w};
                const float w1[4] = {wB[q].x, wB[q].y, wB[q].z, wB[q].w};
#pragma unroll
                for (int i = 0; i < 8; ++i) {
                    const float av = ((const float*)&a4[i])[q];
#pragma unroll
                    for (int j = 0; j < 4; ++j)
                        acc[i][j] = fmaf(av, w0[j], acc[i][j]);
#pragma unroll
                    for (int j = 0; j < 4; ++j)
                        acc[i][4 + j] = fmaf(av, w1[j], acc[i][4 + j]);
                }
            }
        }
    }

#pragma unroll
    for (int i = 0; i < 8; ++i) {
        int m = bm + ty + 16 * i;
        if (m >= M) continue;
        // col group 0: bn + 4tx .. +3
        {
            int n0 = bn + 4 * tx;
            if (n0 + 3 < N) {
                float4 o;
                float x0 = acc[i][0] + bias[n0 + 0];
                float x1 = acc[i][1] + bias[n0 + 1];
                float x2 = acc[i][2] + bias[n0 + 2];
                float x3 = acc[i][3] + bias[n0 + 3];
                if (SILU) { x0 = silu_np(x0); x1 = silu_np(x1); x2 = silu_np(x2); x3 = silu_np(x3); }
                o.x = x0; o.y = x1; o.z = x2; o.w = x3;
                *(float4*)&C[(size_t)m * N + n0] = o;
            } else {
#pragma unroll
                for (int j = 0; j < 4; ++j) {
                    int n = n0 + j;
                    if (n < N) {
                        float x = acc[i][j] + bias[n];
                        if (SILU) x = silu_np(x);
                        C[(size_t)m * N + n] = x;
                    }
                }
            }
        }
        // col group 1: bn + 64 + 4tx .. +3
        {
            int n1 = bn + 64 + 4 * tx;
            if (n1 + 3 < N) {
                float4 o;
                float x0 = acc[i][4] + bias[n1 + 0];
                float x1 = acc[i][5] + bias[n1 + 1];
                float x2 = acc[i][6] + bias[n1 + 2];
                float x3 = acc[i][7] + bias[n1 + 3];
                if (SILU) { x0 = silu_np(x0); x1 = silu_np(x1); x2 = silu_np(x2); x3 = silu_np(x3); }
                o.x = x0; o.y = x1; o.z = x2; o.w = x3;
                *(float4*)&C[(size_t)m * N + n1] = o;
            } else {
#pragma unroll
                for (int j = 0; j < 4; ++j) {
                    int n = n1 + j;
                    if (n < N) {
                        float x = acc[i][4 + j] + bias[n];
                        if (SILU) x = silu_np(x);
                        C[(size_t)m * N + n] = x;
                    }
                }
            }
        }
    }
}

// ---------------- gemm64: 64x64 tile, 4x4/thread — for small-N layers (d3: N=96) -----------
// Same k = 32p + 4kq + q ascending chain per output => bit-identical values.
template <bool SILU>
__global__ __launch_bounds__(256) void gemm64(const float* __restrict__ A,
                                              const float* __restrict__ W,
                                              const float* __restrict__ bias,
                                              float* __restrict__ C,
                                              int M, int N, int K) {
    __shared__ __align__(16) float As[64][36];
    __shared__ __align__(16) float Ws[32][68];
    const int t = threadIdx.x;
    const int tx = t & 15, ty = t >> 4;
    const int bm = blockIdx.y * 64, bn = blockIdx.x * 64;

    float acc[4][4];
#pragma unroll
    for (int i = 0; i < 4; ++i)
#pragma unroll
        for (int j = 0; j < 4; ++j) acc[i][j] = 0.0f;

    const int nPanels = (K + 31) / 32;
    float ra[8], rw[8];

    {
        const int k0 = 0;
#pragma unroll
        for (int it = 0; it < 8; ++it) {
            int e = t + 256 * it;
            int m = e >> 5, kk = e & 31;
            int mm = bm + m; if (mm >= M) mm = M - 1;
            int kc = k0 + kk;
            ra[it] = (kc < K) ? A[(size_t)mm * K + kc] : 0.0f;
            int r = e >> 6, c = e & 63;
            int n = bn + c;
            int kr = k0 + r;
            rw[it] = (kr < K && n < N) ? W[(size_t)kr * N + n] : 0.0f;
        }
    }

    for (int p = 0; p < nPanels; ++p) {
        __syncthreads();
#pragma unroll
        for (int it = 0; it < 8; ++it) {
            int e = t + 256 * it;
            As[e >> 5][e & 31] = ra[it];
            Ws[e >> 6][e & 63] = rw[it];
        }
        __syncthreads();

        if (p + 1 < nPanels) {
            const int k0 = (p + 1) * 32;
#pragma unroll
            for (int it = 0; it < 8; ++it) {
                int e = t + 256 * it;
                int m = e >> 5, kk = e & 31;
                int mm = bm + m; if (mm >= M) mm = M - 1;
                int kc = k0 + kk;
                ra[it] = (kc < K) ? A[(size_t)mm * K + kc] : 0.0f;
                int r = e >> 6, c = e & 63;
                int n = bn + c;
                int kr = k0 + r;
                rw[it] = (kr < K && n < N) ? W[(size_t)kr * N + n] : 0.0f;
            }
        }

#pragma unroll
        for (int kq = 0; kq < 8; ++kq) {
            float4 a4[4], w4[4];
#pragma unroll
            for (int i = 0; i < 4; ++i)
                a4[i] = *(const float4*)&As[4 * ty + i][4 * kq];
#pragma unroll
            for (int q = 0; q < 4; ++q)
                w4[q] = *(const float4*)&Ws[4 * kq + q][4 * tx];
#pragma unroll
            for (int q = 0; q < 4; ++q) {
                const float wv[4] = {w4[q].x, w4[q].y, w4[q].z, w4[q].w};
                const float av[4] = {((const float*)&a4[0])[q], ((const float*)&a4[1])[q],
                                     ((const float*)&a4[2])[q], ((const float*)&a4[3])[q]};
#pragma unroll
                for (int i = 0; i < 4; ++i)
#pragma unroll
                    for (int j = 0; j < 4; ++j)
                        acc[i][j] = fmaf(av[i], wv[j], acc[i][j]);
            }
        }
    }

#pragma unroll
    for (int i = 0; i < 4; ++i) {
        int m = bm + 4 * ty + i;
#pragma unroll
        for (int j = 0; j < 4; ++j) {
            int n = bn + 4 * tx + j;
            if (m < M && n < N) {
                float x = acc[i][j] + bias[n];
                if (SILU) x = silu_np(x);
                C[(size_t)m * N + n] = x;
            }
        }
    }
}

// ---------------- np pairwise sum-of-squares over 128 (8-acc unrolled) ----------------
__device__ __forceinline__ float pairwise128_sq(const float* __restrict__ x, int stride) {
    float r0 = x[0*stride]*x[0*stride], r1 = x[1*stride]*x[1*stride],
          r2 = x[2*stride]*x[2*stride], r3 = x[3*stride]*x[3*stride],
          r4 = x[4*stride]*x[4*stride], r5 = x[5*stride]*x[5*stride],
          r6 = x[6*stride]*x[6*stride], r7 = x[7*stride]*x[7*stride];
    for (int i = 8; i < 128; i += 8) {
        r0 += x[(i+0)*stride]*x[(i+0)*stride];
        r1 += x[(i+1)*stride]*x[(i+1)*stride];
        r2 += x[(i+2)*stride]*x[(i+2)*stride];
        r3 += x[(i+3)*stride]*x[(i+3)*stride];
        r4 += x[(i+4)*stride]*x[(i+4)*stride];
        r5 += x[(i+5)*stride]*x[(i+5)*stride];
        r6 += x[(i+6)*stride]*x[(i+6)*stride];
        r7 += x[(i+7)*stride]*x[(i+7)*stride];
    }
    return ((r0 + r1) + (r2 + r3)) + ((r4 + r5) + (r6 + r7));
}

__global__ void code_t2(const float* __restrict__ cb, float* __restrict__ t2, int K) {
    int k = blockIdx.x * 256 + threadIdx.x;
    if (k >= K) return;
    t2[k] = pairwise128_sq(cb + (size_t)k * DD, 1);
}

// ---------------- cb_pack: pair-interleave codebook for packed-FMA operands ----------------
__global__ void cb_pack(const float* __restrict__ cb, float* __restrict__ cbP, int total) {
    int gid = blockIdx.x * 256 + threadIdx.x;
    if (gid >= total) return;
    int pair = gid >> 8;
    int r = gid & 255;
    int d = r >> 1, w = r & 1;
    cbP[gid] = cb[(size_t)(2 * pair + w) * DD + d];
}

// ---------------- vq_g88p: latents in LDS, packed-pair codebook from L1, v_pk_fma_f32 ------
// (round-10 proven: 831us, VALUBusy 73%, no spill. unchanged)
#define VQG_ROWS 128
#define VQG_CPP  256
#define VQG_LT   132

__global__ __launch_bounds__(512) void vq_g88p(const float* __restrict__ lat,
                                               const float* __restrict__ cbP,
                                               const float* __restrict__ t2,
                                               float* __restrict__ pbv,
                                               int* __restrict__ pbk,
                                               int K, int rows_total) {
    __shared__ __align__(16) float Ls[VQG_ROWS][VQG_LT];   // 67584 B
    __shared__ float T1s[VQG_ROWS];
    __shared__ float bwv[8][VQG_ROWS];
    __shared__ int   bwk[8][VQG_ROWS];

    const int t = threadIdx.x;
    const int tx = t & 15, ty = t >> 4;       // tx: 8-row group (16), ty: code group (32)
    const int wave = t >> 6, lane = t & 63;
    const int r0 = blockIdx.x * VQG_ROWS;

#pragma unroll
    for (int it = 0; it < 8; ++it) {
        int g = t + 512 * it;                 // 4096 float4s = 128 rows x 32 quads
        int r = g >> 5, dq = g & 31;
        int rr = r0 + r; if (rr >= rows_total) rr = rows_total - 1;
        const float4 lv = *(const float4*)(lat + (size_t)rr * DD + 4 * dq);
        *(float4*)&Ls[r][4 * dq] = lv;
    }
    __syncthreads();

    if (t < VQG_ROWS) {
        const float* xr = &Ls[t][0];
        float4 q0 = *(const float4*)&xr[0];
        float4 q1 = *(const float4*)&xr[4];
        float a0 = q0.x*q0.x, a1 = q0.y*q0.y, a2 = q0.z*q0.z, a3 = q0.w*q0.w;
        float a4 = q1.x*q1.x, a5 = q1.y*q1.y, a6 = q1.z*q1.z, a7 = q1.w*q1.w;
#pragma unroll
        for (int i = 1; i < 16; ++i) {
            q0 = *(const float4*)&xr[8 * i];
            q1 = *(const float4*)&xr[8 * i + 4];
            a0 += q0.x*q0.x; a1 += q0.y*q0.y; a2 += q0.z*q0.z; a3 += q0.w*q0.w;
            a4 += q1.x*q1.x; a5 += q1.y*q1.y; a6 += q1.z*q1.z; a7 += q1.w*q1.w;
        }
        T1s[t] = ((a0 + a1) + (a2 + a3)) + ((a4 + a5) + (a6 + a7));
    }
    __syncthreads();

    float t1r[8];
#pragma unroll
    for (int i = 0; i < 8; ++i) t1r[i] = T1s[tx + 16 * i];

    float bestv[8]; int bestk[8];
#pragma unroll
    for (int i = 0; i < 8; ++i) { bestv[i] = 3.4e38f; bestk[i] = 0; }

    const int NP = K / VQG_CPP;
#pragma unroll 1
    for (int p = 0; p < NP; ++p) {
        const int kp = p * VQG_CPP;
        const int cbase = kp + 8 * ty;        // this thread's 8 contiguous codes (4 pairs)
        const float* cp0 = cbP + (size_t)cbase * DD;   // = pair (cbase/2) * 256 floats
        float t2v[8];
#pragma unroll
        for (int j = 0; j < 8; ++j) t2v[j] = t2[cbase + j];

        f2v s2[8][4];
#pragma unroll
        for (int i = 0; i < 8; ++i)
#pragma unroll
            for (int m = 0; m < 4; ++m) s2[i][m] = (f2v)(0.0f);

#pragma unroll 4
        for (int dq = 0; dq < 32; ++dq) {     // ascending d: exact chain order per lane
            float4 u0[4], u1[4];
#pragma unroll
            for (int m = 0; m < 4; ++m) {
                u0[m] = *(const float4*)(cp0 + m * 256 + 8 * dq);
                u1[m] = *(const float4*)(cp0 + m * 256 + 8 * dq + 4);
            }
#pragma unroll
            for (int i = 0; i < 8; ++i) {
                const float4 la = *(const float4*)&Ls[tx + 16 * i][4 * dq];
                const f2v lx = {la.x, la.x}, ly = {la.y, la.y};
                const f2v lz = {la.z, la.z}, lw = {la.w, la.w};
#pragma unroll
                for (int m = 0; m < 4; ++m) {
                    const f2v c0 = {u0[m].x, u0[m].y};   // d = 4dq+0
                    const f2v c1 = {u0[m].z, u0[m].w};   // d = 4dq+1
                    const f2v c2 = {u1[m].x, u1[m].y};   // d = 4dq+2
                    const f2v c3 = {u1[m].z, u1[m].w};   // d = 4dq+3
                    s2[i][m] = __builtin_elementwise_fma(lx, c0, s2[i][m]);
                    s2[i][m] = __builtin_elementwise_fma(ly, c1, s2[i][m]);
                    s2[i][m] = __builtin_elementwise_fma(lz, c2, s2[i][m]);
                    s2[i][m] = __builtin_elementwise_fma(lw, c3, s2[i][m]);
                }
            }
        }

#pragma unroll
        for (int i = 0; i < 8; ++i) {
            const float tt1 = t1r[i];
#pragma unroll
            for (int m = 0; m < 4; ++m) {     // ascending code: 2m (lane0), 2m+1 (lane1)
                const int c0 = cbase + 2 * m;
                const float d0 = (tt1 + t2v[2 * m + 0]) - 2.0f * s2[i][m].x;
                const float d1 = (tt1 + t2v[2 * m + 1]) - 2.0f * s2[i][m].y;
                if (d0 < bestv[i]) { bestv[i] = d0; bestk[i] = c0; }
                if (d1 < bestv[i]) { bestv[i] = d1; bestk[i] = c0 + 1; }
            }
        }
    }

#pragma unroll
    for (int off = 16; off <= 32; off <<= 1) {
#pragma unroll
        for (int i = 0; i < 8; ++i) {
            float vv = __shfl_xor(bestv[i], off);
            int kk = __shfl_xor(bestk[i], off);
            if (vv < bestv[i] || (vv == bestv[i] && kk < bestk[i])) {
                bestv[i] = vv; bestk[i] = kk;
            }
        }
    }
    if (lane < 16) {
#pragma unroll
        for (int i = 0; i < 8; ++i) {
            bwv[wave][tx + 16 * i] = bestv[i];
            bwk[wave][tx + 16 * i] = bestk[i];
        }
    }
    __syncthreads();
    if (t < VQG_ROWS) {
        float bv = bwv[0][t]; int bk = bwk[0][t];
#pragma unroll
        for (int w = 1; w < 8; ++w) {          // lexicographic (v,k): global first-min
            float v = bwv[w][t]; int k = bwk[w][t];
            if (v < bv || (v == bv && k < bk)) { bv = v; bk = k; }
        }
        if (r0 + t < rows_total) {
            pbv[r0 + t] = bv;
            pbk[r0 + t] = bk;
        }
    }
}

// ---------------- vq_np4: fallback for shapes vq_g88p doesn't cover (unchanged) ------------
__global__ __launch_bounds__(512) void vq_np4(const float* __restrict__ lat,
                                              const float* __restrict__ cb,
                                              const float* __restrict__ t2,
                                              float* __restrict__ pbv,
                                              int* __restrict__ pbk,
                                              int K, int Kc, int rows_total) {
    __shared__ __align__(16) float Ls[128][68];   // [d][row]  34816 B
    __shared__ __align__(16) float Cs[128][68];   // [d][code] 34816 B (64 codes used)
    __shared__ float T1s[64];
    __shared__ float T2s[64];
    __shared__ float bwv[8][68];                  // per-wave best per row
    __shared__ int   bwk[8][68];

    const int t = threadIdx.x;
    const int tx = t & 15, ty = t >> 4;           // tx: row group (4), ty: code group (2)
    const int wave = t >> 6, lane = t & 63;
    const int r0 = blockIdx.x * 64;
    const int kbeg = blockIdx.y * Kc;
    const int kend = kbeg + Kc;

#pragma unroll
    for (int it = 0; it < 4; ++it) {
        int g = t + 512 * it;
        int row = g >> 5, dq = g & 31;
        int rr = r0 + row; if (rr >= rows_total) rr = rows_total - 1;
        const float4 v = *(const float4*)(lat + (size_t)rr * DD + 4 * dq);
        Ls[4*dq+0][row] = v.x; Ls[4*dq+1][row] = v.y;
        Ls[4*dq+2][row] = v.z; Ls[4*dq+3][row] = v.w;
    }
    __syncthreads();
    if (t < 64) T1s[t] = pairwise128_sq(&Ls[0][t], 68);

    float bestv[4]; int bestk[4];
#pragma unroll
    for (int r = 0; r < 4; ++r) { bestv[r] = 3.4e38f; bestk[r] = 0; }

    float4 pc[4];
    float pt2 = 0.0f;
#pragma unroll
    for (int it = 0; it < 4; ++it) {
        int g = t + 512 * it;
        int c = g >> 5, dq = g & 31;
        int cc = kbeg + c; if (cc >= K) cc = K - 1;
        pc[it] = *(const float4*)(cb + (size_t)cc * DD + 4 * dq);
    }
    if (t < 64) { int cc = kbeg + t; if (cc >= K) cc = K - 1; pt2 = t2[cc]; }

    for (int k0 = kbeg; k0 < kend; k0 += 64) {
        __syncthreads();
#pragma unroll
        for (int it = 0; it < 4; ++it) {
            int g = t + 512 * it;
            int c = g >> 5, dq = g & 31;
            Cs[4*dq+0][c] = pc[it].x; Cs[4*dq+1][c] = pc[it].y;
            Cs[4*dq+2][c] = pc[it].z; Cs[4*dq+3][c] = pc[it].w;
        }
        if (t < 64) T2s[t] = pt2;
        __syncthreads();

        if (k0 + 64 < kend) {
            const int kn = k0 + 64;
#pragma unroll
            for (int it = 0; it < 4; ++it) {
                int g = t + 512 * it;
                int c = g >> 5, dq = g & 31;
                int cc = kn + c; if (cc >= K) cc = K - 1;
                pc[it] = *(const float4*)(cb + (size_t)cc * DD + 4 * dq);
            }
            if (t < 64) { int cc = kn + t; if (cc >= K) cc = K - 1; pt2 = t2[cc]; }
        }

        float s[4][2];
#pragma unroll
        for (int r = 0; r < 4; ++r) { s[r][0] = 0.0f; s[r][1] = 0.0f; }

#pragma unroll 8
        for (int d = 0; d < 128; ++d) {
            const float4 a4 = *(const float4*)&Ls[d][4 * tx];
            const float2 c2 = *(const float2*)&Cs[d][2 * ty];
            const float av[4] = {a4.x, a4.y, a4.z, a4.w};
#pragma unroll
            for (int r = 0; r < 4; ++r) {
                s[r][0] = fmaf(av[r], c2.x, s[r][0]);
                s[r][1] = fmaf(av[r], c2.y, s[r][1]);
            }
        }

#pragma unroll
        for (int r = 0; r < 4; ++r) {
            const float t1 = T1s[4 * tx + r];
#pragma unroll
            for (int j = 0; j < 2; ++j) {
                int kc = k0 + 2 * ty + j;
                float dist = (t1 + T2s[2 * ty + j]) - 2.0f * s[r][j];
                if (kc < K && dist < bestv[r]) { bestv[r] = dist; bestk[r] = kc; }
            }
        }
    }

#pragma unroll
    for (int off = 16; off <= 32; off <<= 1) {
#pragma unroll
        for (int r = 0; r < 4; ++r) {
            float vv = __shfl_xor(bestv[r], off);
            int kk = __shfl_xor(bestk[r], off);
            if (vv < bestv[r] || (vv == bestv[r] && kk < bestk[r])) {
                bestv[r] = vv; bestk[r] = kk;
            }
        }
    }
    if (lane < 16) {
#pragma unroll
        for (int r = 0; r < 4; ++r) {
            bwv[wave][4 * lane + r] = bestv[r];
            bwk[wave][4 * lane + r] = bestk[r];
        }
    }
    __syncthreads();
    if (t < 64) {
        float bv = bwv[0][t]; int bk = bwk[0][t];
#pragma unroll
        for (int w = 1; w < 8; ++w) {
            float v = bwv[w][t]; int k = bwk[w][t];
            if (v < bv || (v == bv && k < bk)) { bv = v; bk = k; }
        }
        if (r0 + t < rows_total) {
            size_t o = (size_t)blockIdx.y * rows_total + (r0 + t);
            pbv[o] = bv;
            pbk[o] = bk;
        }
    }
}

// combine K-split partials: ascending split, strict < => global first-min; fused vq loss
__global__ __launch_bounds__(256) void vq_combine(const float* __restrict__ pbv,
                                                  const int* __restrict__ pbk,
                                                  int S, int rows,
                                                  int* __restrict__ indices,
                                                  double* __restrict__ acc) {
    int r = blockIdx.x * 256 + threadIdx.x;
    float bv = 3.4e38f; int bk = 0;
    if (r < rows) {
        for (int s = 0; s < S; ++s) {
            float v = pbv[(size_t)s * rows + r];
            int k = pbk[(size_t)s * rows + r];
            if (v < bv) { bv = v; bk = k; }
        }
        indices[r] = bk;
    }
    __shared__ double red[256];
    red[threadIdx.x] = (r < rows) ? (double)bv : 0.0;
    __syncthreads();
    for (int s = 128; s > 0; s >>= 1) {
        if (threadIdx.x < s) red[threadIdx.x] += red[threadIdx.x + s];
        __syncthreads();
    }
    if (threadIdx.x == 0) atomicAdd(acc, red[0]);
}

// ---------------- Q gather ----------------
__global__ void q_gather(const int* __restrict__ idx, const float* __restrict__ cb,
                         float* __restrict__ Q, int count, int nlat) {
    int gid = blockIdx.x * 256 + threadIdx.x;
    if (gid >= count) return;
    int m = gid >> 11;            // / LAT (2048, verified)
    int j = gid & 2047;
    int code = idx[m * nlat + (j >> 7)];
    Q[gid] = cb[((size_t)code << 7) + (j & 127)];
}

// ---------------- recon loss + f32 write ----------------
__global__ __launch_bounds__(256) void recon_out(const float* __restrict__ recon,
                                                 const float* __restrict__ actions,
                                                 float* __restrict__ out,
                                                 double* __restrict__ acc, int count) {
    int gid = blockIdx.x * 256 + threadIdx.x;
    double sq = 0.0;
    if (gid < count) {
        float rv = recon[gid];
        float av = actions[gid];
        double diff = (double)rv - (double)av;
        out[gid] = rv;
        sq = diff * diff;
    }
    __shared__ double red[256];
    red[threadIdx.x] = sq;
    __syncthreads();
    for (int s = 128; s > 0; s >>= 1) {
        if (threadIdx.x < s) red[threadIdx.x] += red[threadIdx.x + s];
        __syncthreads();
    }
    if (threadIdx.x == 0) atomicAdd(acc + 1, red[0]);
}

__global__ void idx_out(const int* __restrict__ idx, float* __restrict__ out, int count) {
    int gid = blockIdx.x * 256 + threadIdx.x;
    if (gid < count) out[gid] = (float)idx[gid];
}

__global__ void finalize(const double* __restrict__ acc, float* __restrict__ out,
                         double vq_den, double rec_den) {
    double vq = 1.25 * acc[0] / vq_den;
    double rl = acc[1] / rec_den;
    out[0] = (float)vq;
    out[1] = (float)rl;
    out[2] = (float)(rl + vq);
}

static inline int ceildiv(int a, int b) { return (a + b - 1) / b; }

// ---------------- launch ----------------
extern "C" void kernel_launch(void* const* d_in, const int* in_sizes, int n_in,
                              void* d_out, int out_size, void* d_ws, size_t ws_size,
                              hipStream_t stream) {
    const float* actions = (const float*)d_in[0];
    const float* e_w1 = (const float*)d_in[1];
    const float* e_b1 = (const float*)d_in[2];
    const float* e_w2 = (const float*)d_in[3];
    const float* e_b2 = (const float*)d_in[4];
    const float* e_w3 = (const float*)d_in[5];
    const float* e_b3 = (const float*)d_in[6];
    const float* cb   = (const float*)d_in[7];
    const float* d_w1 = (const float*)d_in[8];
    const float* d_b1 = (const float*)d_in[9];
    const float* d_w2 = (const float*)d_in[10];
    const float* d_b2 = (const float*)d_in[11];
    const float* d_w3 = (const float*)d_in[12];
    const float* d_b3 = (const float*)d_in[13];
    float* out = (float*)d_out;

    const int FLAT = in_sizes[13];
    const int B    = in_sizes[0] / FLAT;
    const int HID  = in_sizes[2];
    const int LAT  = in_sizes[6];
    const int K    = in_sizes[7] / DD;
    const int NL   = LAT / DD;

    const bool g88 = (K % VQG_CPP == 0);
    const int S = 1;
    const int Kc = K;

    int CHUNK = B;                                // full-batch; halve only if ws too small
    auto need = [&](int ch) -> size_t {
        return (size_t)ch * HID * 4 * 2 + (size_t)ch * LAT * 4 * 2
             + (size_t)ch * HID * 4 * 2 + (size_t)ch * FLAT * 4
             + (size_t)K * 4 + (size_t)K * DD * 4 + 64 + (size_t)B * NL * 4
             + (size_t)ch * NL * S * 8;
    };
    while (CHUNK > 16 && need(CHUNK) > ws_size) CHUNK >>= 1;
    if (need(CHUNK) > ws_size) {
        plant_diag<<<1, 64, 0, stream>>>(2222.0f, out);
        return;
    }
    const int NCHUNK = ceildiv(B, CHUNK);

    char* ws = (char*)d_ws;
    size_t off = 0;
    float* h1c  = (float*)(ws + off); off += (size_t)CHUNK * HID * 4;
    float* h2c  = (float*)(ws + off); off += (size_t)CHUNK * HID * 4;
    float* latc = (float*)(ws + off); off += (size_t)CHUNK * LAT * 4;
    float* Qc   = (float*)(ws + off); off += (size_t)CHUNK * LAT * 4;
    float* g1c  = (float*)(ws + off); off += (size_t)CHUNK * HID * 4;
    float* g2c  = (float*)(ws + off); off += (size_t)CHUNK * HID * 4;
    float* recc = (float*)(ws + off); off += (size_t)CHUNK * FLAT * 4;
    float* t2   = (float*)(ws + off); off += (size_t)K * 4;
    float* cbP  = (float*)(ws + off); off += (size_t)K * DD * 4;
    double* acc = (double*)(ws + off); off += 64;
    int*   idx  = (int*)(ws + off);   off += (size_t)B * NL * 4;
    float* pbv  = (float*)(ws + off); off += (size_t)CHUNK * NL * S * 4;
    int*   pbk  = (int*)(ws + off);

    zero_acc<<<1, 64, 0, stream>>>(acc);
    code_t2<<<ceildiv(K, 256), 256, 0, stream>>>(cb, t2, K);
    if (g88) {
        cb_pack<<<ceildiv(K * DD, 256), 256, 0, stream>>>(cb, cbP, K * DD);
    }

    auto GEMM = [&](bool silu, const float* Araw, const float* Wt, const float* bias,
                    float* Cout, int M, int N, int Kd) {
        if (N < 128) {                        // small-N: 64x64 tile (d3)
            dim3 grid(ceildiv(N, 64), ceildiv(M, 64));
            if (silu) gemm64<true><<<grid, 256, 0, stream>>>(Araw, Wt, bias, Cout, M, N, Kd);
            else      gemm64<false><<<grid, 256, 0, stream>>>(Araw, Wt, bias, Cout, M, N, Kd);
        } else {                              // 128x128 tile, 8x8/thread
            dim3 grid(ceildiv(N, 128), ceildiv(M, 128));
            if (silu) gemm88<true><<<grid, 256, 0, stream>>>(Araw, Wt, bias, Cout, M, N, Kd);
            else      gemm88<false><<<grid, 256, 0, stream>>>(Araw, Wt, bias, Cout, M, N, Kd);
        }
    };

    for (int c = 0; c < NCHUNK; ++c) {
        const int r0 = c * CHUNK;
        const int cbR = (B - r0 < CHUNK) ? (B - r0) : CHUNK;
        const float* act_c = actions + (size_t)r0 * FLAT;
        int* idx_c = idx + (size_t)r0 * NL;
        const int rows = cbR * NL;

        // encoder: 128x128-tile exact-chain GEMMs (bit-identical chains)
        GEMM(true,  act_c, e_w1, e_b1, h1c, cbR, HID, FLAT);
        GEMM(true,  h1c,   e_w2, e_b2, h2c, cbR, HID, HID);
        GEMM(false, h2c,   e_w3, e_b3, latc, cbR, LAT, HID);

        // VQ: packed-pair codebook + v_pk_fma_f32 kernel (bit-identical) + exact combine
        if (g88) {
            vq_g88p<<<ceildiv(rows, VQG_ROWS), 512, 0, stream>>>(
                latc, cbP, t2, pbv, pbk, K, rows);
        } else {
            vq_np4<<<dim3(ceildiv(rows, 64), S), 512, 0, stream>>>(
                latc, cb, t2, pbv, pbk, K, Kc, rows);
        }
        vq_combine<<<ceildiv(rows, 256), 256, 0, stream>>>(pbv, pbk, S, rows, idx_c, acc);

        // decoder
        q_gather<<<ceildiv(cbR * LAT, 256), 256, 0, stream>>>(idx_c, cb, Qc, cbR * LAT, NL);
        GEMM(true,  Qc,  d_w1, d_b1, g1c, cbR, HID, LAT);
        GEMM(true,  g1c, d_w2, d_b2, g2c, cbR, HID, HID);
        GEMM(false, g2c, d_w3, d_b3, recc, cbR, FLAT, HID);

        recon_out<<<ceildiv(cbR * FLAT, 256), 256, 0, stream>>>(
            recc, act_c, out + (size_t)r0 * FLAT, acc, cbR * FLAT);
    }

    // f32 packing: [ recon B*FLAT | indices B*NL | vq, recon_loss, loss ]
    idx_out<<<ceildiv(B * NL, 256), 256, 0, stream>>>(idx, out + (size_t)B * FLAT, B * NL);
    finalize<<<1, 1, 0, stream>>>(acc, out + (size_t)B * FLAT + (size_t)B * NL,
                                  (double)B * NL * DD, (double)B * FLAT);
}

// Round 14
// 1730.820 us; speedup vs baseline: 1.5681x; 1.5681x over previous
//
#include <hip/hip_runtime.h>
#include <hip/hip_bf16.h>

#define DD 128            // codebook dim

typedef float f2v __attribute__((ext_vector_type(2)));

__global__ void plant_diag(float val, float* out) {
    if (threadIdx.x == 0 && blockIdx.x == 0) out[0] = val;
}

__global__ void zero_acc(double* acc) {
    if (threadIdx.x == 0 && blockIdx.x == 0) { acc[0] = 0.0; acc[1] = 0.0; }
}

// ---------------- silu mimicking np: x * (1/(1+exp(-x))), each op f32-rounded ----------------
__device__ __forceinline__ float silu_np(float x) {
    float e = (float)exp(-(double)x);   // correctly-rounded f32 exp
    float u = 1.0f + e;
    float v = 1.0f / u;
    return x * v;
}

// ---------------- gemm_db: C = act(A@W + b) — 128x64 tile, 8x4/thread, EXACT chains --------
// (round-7/9/10 proven LDS-staged version: 92 VGPR, ~132us big dispatch. unchanged —
//  three structural variants (W-direct r8, W-packed r11, 128x128 r13) all regressed via
//  VGPR pressure or exposed latency; this is the measured local optimum.)
template <bool SILU>
__global__ __launch_bounds__(256) void gemm_db(const float* __restrict__ A,
                                               const float* __restrict__ W,
                                               const float* __restrict__ bias,
                                               float* __restrict__ C,
                                               int M, int N, int K) {
    __shared__ __align__(16) float As[128][36];
    __shared__ __align__(16) float Ws[32][68];
    const int t = threadIdx.x;
    const int tx = t & 15, ty = t >> 4;       // tx: 4 cols, ty: 8 rows (ty+16i)
    const int bm = blockIdx.y * 128, bn = blockIdx.x * 64;

    float acc[8][4];
#pragma unroll
    for (int i = 0; i < 8; ++i)
#pragma unroll
        for (int j = 0; j < 4; ++j) acc[i][j] = 0.0f;

    const int nPanels = (K + 31) / 32;
    float ra[16], rw[8];

    {
        const int k0 = 0;
#pragma unroll
        for (int it = 0; it < 16; ++it) {     // A-panel: 128 x 32
            int e = t + 256 * it;
            int m = e >> 5, kk = e & 31;
            int mm = bm + m; if (mm >= M) mm = M - 1;
            int kc = k0 + kk;
            ra[it] = (kc < K) ? A[(size_t)mm * K + kc] : 0.0f;
        }
#pragma unroll
        for (int it = 0; it < 8; ++it) {      // W-panel: 32 x 64
            int e = t + 256 * it;
            int r = e >> 6, c = e & 63;
            int n = bn + c;
            int kr = k0 + r;
            rw[it] = (kr < K && n < N) ? W[(size_t)kr * N + n] : 0.0f;
        }
    }

    for (int p = 0; p < nPanels; ++p) {
        __syncthreads();
#pragma unroll
        for (int it = 0; it < 16; ++it) {
            int e = t + 256 * it;
            As[e >> 5][e & 31] = ra[it];
        }
#pragma unroll
        for (int it = 0; it < 8; ++it) {
            int e = t + 256 * it;
            Ws[e >> 6][e & 63] = rw[it];
        }
        __syncthreads();

        if (p + 1 < nPanels) {
            const int k0 = (p + 1) * 32;
#pragma unroll
            for (int it = 0; it < 16; ++it) {
                int e = t + 256 * it;
                int m = e >> 5, kk = e & 31;
                int mm = bm + m; if (mm >= M) mm = M - 1;
                int kc = k0 + kk;
                ra[it] = (kc < K) ? A[(size_t)mm * K + kc] : 0.0f;
            }
#pragma unroll
            for (int it = 0; it < 8; ++it) {
                int e = t + 256 * it;
                int r = e >> 6, c = e & 63;
                int n = bn + c;
                int kr = k0 + r;
                rw[it] = (kr < K && n < N) ? W[(size_t)kr * N + n] : 0.0f;
            }
        }

#pragma unroll
        for (int kq = 0; kq < 8; ++kq) {
            float4 a4[8], w4[4];
#pragma unroll
            for (int i = 0; i < 8; ++i)
                a4[i] = *(const float4*)&As[ty + 16 * i][4 * kq];
#pragma unroll
            for (int q = 0; q < 4; ++q)
                w4[q] = *(const float4*)&Ws[4 * kq + q][4 * tx];
#pragma unroll
            for (int q = 0; q < 4; ++q) {
                const float wv[4] = {w4[q].x, w4[q].y, w4[q].z, w4[q].w};
#pragma unroll
                for (int i = 0; i < 8; ++i) {
                    const float av = ((const float*)&a4[i])[q];
#pragma unroll
                    for (int j = 0; j < 4; ++j)
                        acc[i][j] = fmaf(av, wv[j], acc[i][j]);
                }
            }
        }
    }

#pragma unroll
    for (int i = 0; i < 8; ++i) {
        int m = bm + ty + 16 * i;
#pragma unroll
        for (int j = 0; j < 4; ++j) {
            int n = bn + 4 * tx + j;
            if (m < M && n < N) {
                float x = acc[i][j] + bias[n];
                if (SILU) x = silu_np(x);
                C[(size_t)m * N + n] = x;
            }
        }
    }
}

// ---------------- gemm64r: 64x64 tile d3 GEMM with FUSED recon write + loss ----------------
// Same k = 32p + 4kq + q ascending chain per output as gemm_db => bit-identical recon
// values. Writes recon directly to out and accumulates sum((recon-actions)^2) in double
// (block LDS tree + one atomicAdd — same commutative double accumulation as the old
// standalone recon_out; atomic order was already nondeterministic). Also fixes d3's grid
// starvation: N=96 -> 128 blocks instead of 64.
__global__ __launch_bounds__(256) void gemm64r(const float* __restrict__ A,
                                               const float* __restrict__ W,
                                               const float* __restrict__ bias,
                                               const float* __restrict__ actions,
                                               float* __restrict__ out,
                                               double* __restrict__ accg,
                                               int M, int N, int K) {
    __shared__ __align__(16) float As[64][36];
    __shared__ __align__(16) float Ws[32][68];
    __shared__ double red[256];
    const int t = threadIdx.x;
    const int tx = t & 15, ty = t >> 4;
    const int bm = blockIdx.y * 64, bn = blockIdx.x * 64;

    float acc[4][4];
#pragma unroll
    for (int i = 0; i < 4; ++i)
#pragma unroll
        for (int j = 0; j < 4; ++j) acc[i][j] = 0.0f;

    const int nPanels = (K + 31) / 32;
    float ra[8], rw[8];

    {
        const int k0 = 0;
#pragma unroll
        for (int it = 0; it < 8; ++it) {
            int e = t + 256 * it;
            int m = e >> 5, kk = e & 31;
            int mm = bm + m; if (mm >= M) mm = M - 1;
            int kc = k0 + kk;
            ra[it] = (kc < K) ? A[(size_t)mm * K + kc] : 0.0f;
            int r = e >> 6, c = e & 63;
            int n = bn + c;
            int kr = k0 + r;
            rw[it] = (kr < K && n < N) ? W[(size_t)kr * N + n] : 0.0f;
        }
    }

    for (int p = 0; p < nPanels; ++p) {
        __syncthreads();
#pragma unroll
        for (int it = 0; it < 8; ++it) {
            int e = t + 256 * it;
            As[e >> 5][e & 31] = ra[it];
            Ws[e >> 6][e & 63] = rw[it];
        }
        __syncthreads();

        if (p + 1 < nPanels) {
            const int k0 = (p + 1) * 32;
#pragma unroll
            for (int it = 0; it < 8; ++it) {
                int e = t + 256 * it;
                int m = e >> 5, kk = e & 31;
                int mm = bm + m; if (mm >= M) mm = M - 1;
                int kc = k0 + kk;
                ra[it] = (kc < K) ? A[(size_t)mm * K + kc] : 0.0f;
                int r = e >> 6, c = e & 63;
                int n = bn + c;
                int kr = k0 + r;
                rw[it] = (kr < K && n < N) ? W[(size_t)kr * N + n] : 0.0f;
            }
        }

#pragma unroll
        for (int kq = 0; kq < 8; ++kq) {
            float4 a4[4], w4[4];
#pragma unroll
            for (int i = 0; i < 4; ++i)
                a4[i] = *(const float4*)&As[4 * ty + i][4 * kq];
#pragma unroll
            for (int q = 0; q < 4; ++q)
                w4[q] = *(const float4*)&Ws[4 * kq + q][4 * tx];
#pragma unroll
            for (int q = 0; q < 4; ++q) {
                const float wv[4] = {w4[q].x, w4[q].y, w4[q].z, w4[q].w};
                const float av[4] = {((const float*)&a4[0])[q], ((const float*)&a4[1])[q],
                                     ((const float*)&a4[2])[q], ((const float*)&a4[3])[q]};
#pragma unroll
                for (int i = 0; i < 4; ++i)
#pragma unroll
                    for (int j = 0; j < 4; ++j)
                        acc[i][j] = fmaf(av[i], wv[j], acc[i][j]);
            }
        }
    }

    double sq = 0.0;
#pragma unroll
    for (int i = 0; i < 4; ++i) {
        int m = bm + 4 * ty + i;
        if (m >= M) continue;
#pragma unroll
        for (int j = 0; j < 4; ++j) {
            int n = bn + 4 * tx + j;
            if (n < N) {
                float x = acc[i][j] + bias[n];       // no silu on d3
                float av = actions[(size_t)m * N + n];
                out[(size_t)m * N + n] = x;
                double diff = (double)x - (double)av;
                sq += diff * diff;
            }
        }
    }
    __syncthreads();                                  // As/Ws reads done; reuse-safe
    red[t] = sq;
    __syncthreads();
    for (int s = 128; s > 0; s >>= 1) {
        if (t < s) red[t] += red[t + s];
        __syncthreads();
    }
    if (t == 0) atomicAdd(accg + 1, red[0]);
}

// ---------------- np pairwise sum-of-squares over 128 (8-acc unrolled) ----------------
__device__ __forceinline__ float pairwise128_sq(const float* __restrict__ x, int stride) {
    float r0 = x[0*stride]*x[0*stride], r1 = x[1*stride]*x[1*stride],
          r2 = x[2*stride]*x[2*stride], r3 = x[3*stride]*x[3*stride],
          r4 = x[4*stride]*x[4*stride], r5 = x[5*stride]*x[5*stride],
          r6 = x[6*stride]*x[6*stride], r7 = x[7*stride]*x[7*stride];
    for (int i = 8; i < 128; i += 8) {
        r0 += x[(i+0)*stride]*x[(i+0)*stride];
        r1 += x[(i+1)*stride]*x[(i+1)*stride];
        r2 += x[(i+2)*stride]*x[(i+2)*stride];
        r3 += x[(i+3)*stride]*x[(i+3)*stride];
        r4 += x[(i+4)*stride]*x[(i+4)*stride];
        r5 += x[(i+5)*stride]*x[(i+5)*stride];
        r6 += x[(i+6)*stride]*x[(i+6)*stride];
        r7 += x[(i+7)*stride]*x[(i+7)*stride];
    }
    return ((r0 + r1) + (r2 + r3)) + ((r4 + r5) + (r6 + r7));
}

__global__ void code_t2(const float* __restrict__ cb, float* __restrict__ t2, int K) {
    int k = blockIdx.x * 256 + threadIdx.x;
    if (k >= K) return;
    t2[k] = pairwise128_sq(cb + (size_t)k * DD, 1);
}

// ---------------- cb_pack: pair-interleave codebook for packed-FMA operands ----------------
__global__ void cb_pack(const float* __restrict__ cb, float* __restrict__ cbP, int total) {
    int gid = blockIdx.x * 256 + threadIdx.x;
    if (gid >= total) return;
    int pair = gid >> 8;
    int r = gid & 255;
    int d = r >> 1, w = r & 1;
    cbP[gid] = cb[(size_t)(2 * pair + w) * DD + d];
}

// ---------------- vq_g88p: latents in LDS, packed-pair codebook from L1, v_pk_fma_f32 ------
// (round-10 proven: 831us, VALUBusy 73%, no spill. unchanged)
#define VQG_ROWS 128
#define VQG_CPP  256
#define VQG_LT   132

__global__ __launch_bounds__(512) void vq_g88p(const float* __restrict__ lat,
                                               const float* __restrict__ cbP,
                                               const float* __restrict__ t2,
                                               float* __restrict__ pbv,
                                               int* __restrict__ pbk,
                                               int K, int rows_total) {
    __shared__ __align__(16) float Ls[VQG_ROWS][VQG_LT];   // 67584 B
    __shared__ float T1s[VQG_ROWS];
    __shared__ float bwv[8][VQG_ROWS];
    __shared__ int   bwk[8][VQG_ROWS];

    const int t = threadIdx.x;
    const int tx = t & 15, ty = t >> 4;       // tx: 8-row group (16), ty: code group (32)
    const int wave = t >> 6, lane = t & 63;
    const int r0 = blockIdx.x * VQG_ROWS;

#pragma unroll
    for (int it = 0; it < 8; ++it) {
        int g = t + 512 * it;                 // 4096 float4s = 128 rows x 32 quads
        int r = g >> 5, dq = g & 31;
        int rr = r0 + r; if (rr >= rows_total) rr = rows_total - 1;
        const float4 lv = *(const float4*)(lat + (size_t)rr * DD + 4 * dq);
        *(float4*)&Ls[r][4 * dq] = lv;
    }
    __syncthreads();

    if (t < VQG_ROWS) {
        const float* xr = &Ls[t][0];
        float4 q0 = *(const float4*)&xr[0];
        float4 q1 = *(const float4*)&xr[4];
        float a0 = q0.x*q0.x, a1 = q0.y*q0.y, a2 = q0.z*q0.z, a3 = q0.w*q0.w;
        float a4 = q1.x*q1.x, a5 = q1.y*q1.y, a6 = q1.z*q1.z, a7 = q1.w*q1.w;
#pragma unroll
        for (int i = 1; i < 16; ++i) {
            q0 = *(const float4*)&xr[8 * i];
            q1 = *(const float4*)&xr[8 * i + 4];
            a0 += q0.x*q0.x; a1 += q0.y*q0.y; a2 += q0.z*q0.z; a3 += q0.w*q0.w;
            a4 += q1.x*q1.x; a5 += q1.y*q1.y; a6 += q1.z*q1.z; a7 += q1.w*q1.w;
        }
        T1s[t] = ((a0 + a1) + (a2 + a3)) + ((a4 + a5) + (a6 + a7));
    }
    __syncthreads();

    float t1r[8];
#pragma unroll
    for (int i = 0; i < 8; ++i) t1r[i] = T1s[tx + 16 * i];

    float bestv[8]; int bestk[8];
#pragma unroll
    for (int i = 0; i < 8; ++i) { bestv[i] = 3.4e38f; bestk[i] = 0; }

    const int NP = K / VQG_CPP;
#pragma unroll 1
    for (int p = 0; p < NP; ++p) {
        const int kp = p * VQG_CPP;
        const int cbase = kp + 8 * ty;        // this thread's 8 contiguous codes (4 pairs)
        const float* cp0 = cbP + (size_t)cbase * DD;   // = pair (cbase/2) * 256 floats
        float t2v[8];
#pragma unroll
        for (int j = 0; j < 8; ++j) t2v[j] = t2[cbase + j];

        f2v s2[8][4];
#pragma unroll
        for (int i = 0; i < 8; ++i)
#pragma unroll
            for (int m = 0; m < 4; ++m) s2[i][m] = (f2v)(0.0f);

#pragma unroll 4
        for (int dq = 0; dq < 32; ++dq) {     // ascending d: exact chain order per lane
            float4 u0[4], u1[4];
#pragma unroll
            for (int m = 0; m < 4; ++m) {
                u0[m] = *(const float4*)(cp0 + m * 256 + 8 * dq);
                u1[m] = *(const float4*)(cp0 + m * 256 + 8 * dq + 4);
            }
#pragma unroll
            for (int i = 0; i < 8; ++i) {
                const float4 la = *(const float4*)&Ls[tx + 16 * i][4 * dq];
                const f2v lx = {la.x, la.x}, ly = {la.y, la.y};
                const f2v lz = {la.z, la.z}, lw = {la.w, la.w};
#pragma unroll
                for (int m = 0; m < 4; ++m) {
                    const f2v c0 = {u0[m].x, u0[m].y};   // d = 4dq+0
                    const f2v c1 = {u0[m].z, u0[m].w};   // d = 4dq+1
                    const f2v c2 = {u1[m].x, u1[m].y};   // d = 4dq+2
                    const f2v c3 = {u1[m].z, u1[m].w};   // d = 4dq+3
                    s2[i][m] = __builtin_elementwise_fma(lx, c0, s2[i][m]);
                    s2[i][m] = __builtin_elementwise_fma(ly, c1, s2[i][m]);
                    s2[i][m] = __builtin_elementwise_fma(lz, c2, s2[i][m]);
                    s2[i][m] = __builtin_elementwise_fma(lw, c3, s2[i][m]);
                }
            }
        }

#pragma unroll
        for (int i = 0; i < 8; ++i) {
            const float tt1 = t1r[i];
#pragma unroll
            for (int m = 0; m < 4; ++m) {     // ascending code: 2m (lane0), 2m+1 (lane1)
                const int c0 = cbase + 2 * m;
                const float d0 = (tt1 + t2v[2 * m + 0]) - 2.0f * s2[i][m].x;
                const float d1 = (tt1 + t2v[2 * m + 1]) - 2.0f * s2[i][m].y;
                if (d0 < bestv[i]) { bestv[i] = d0; bestk[i] = c0; }
                if (d1 < bestv[i]) { bestv[i] = d1; bestk[i] = c0 + 1; }
            }
        }
    }

#pragma unroll
    for (int off = 16; off <= 32; off <<= 1) {
#pragma unroll
        for (int i = 0; i < 8; ++i) {
            float vv = __shfl_xor(bestv[i], off);
            int kk = __shfl_xor(bestk[i], off);
            if (vv < bestv[i] || (vv == bestv[i] && kk < bestk[i])) {
                bestv[i] = vv; bestk[i] = kk;
            }
        }
    }
    if (lane < 16) {
#pragma unroll
        for (int i = 0; i < 8; ++i) {
            bwv[wave][tx + 16 * i] = bestv[i];
            bwk[wave][tx + 16 * i] = bestk[i];
        }
    }
    __syncthreads();
    if (t < VQG_ROWS) {
        float bv = bwv[0][t]; int bk = bwk[0][t];
#pragma unroll
        for (int w = 1; w < 8; ++w) {          // lexicographic (v,k): global first-min
            float v = bwv[w][t]; int k = bwk[w][t];
            if (v < bv || (v == bv && k < bk)) { bv = v; bk = k; }
        }
        if (r0 + t < rows_total) {
            pbv[r0 + t] = bv;
            pbk[r0 + t] = bk;
        }
    }
}

// ---------------- vq_np4: fallback for shapes vq_g88p doesn't cover (unchanged) ------------
__global__ __launch_bounds__(512) void vq_np4(const float* __restrict__ lat,
                                              const float* __restrict__ cb,
                                              const float* __restrict__ t2,
                                              float* __restrict__ pbv,
                                              int* __restrict__ pbk,
                                              int K, int Kc, int rows_total) {
    __shared__ __align__(16) float Ls[128][68];   // [d][row]  34816 B
    __shared__ __align__(16) float Cs[128][68];   // [d][code] 34816 B (64 codes used)
    __shared__ float T1s[64];
    __shared__ float T2s[64];
    __shared__ float bwv[8][68];                  // per-wave best per row
    __shared__ int   bwk[8][68];

    const int t = threadIdx.x;
    const int tx = t & 15, ty = t >> 4;           // tx: row group (4), ty: code group (2)
    const int wave = t >> 6, lane = t & 63;
    const int r0 = blockIdx.x * 64;
    const int kbeg = blockIdx.y * Kc;
    const int kend = kbeg + Kc;

#pragma unroll
    for (int it = 0; it < 4; ++it) {
        int g = t + 512 * it;
        int row = g >> 5, dq = g & 31;
        int rr = r0 + row; if (rr >= rows_total) rr = rows_total - 1;
        const float4 v = *(const float4*)(lat + (size_t)rr * DD + 4 * dq);
        Ls[4*dq+0][row] = v.x; Ls[4*dq+1][row] = v.y;
        Ls[4*dq+2][row] = v.z; Ls[4*dq+3][row] = v.w;
    }
    __syncthreads();
    if (t < 64) T1s[t] = pairwise128_sq(&Ls[0][t], 68);

    float bestv[4]; int bestk[4];
#pragma unroll
    for (int r = 0; r < 4; ++r) { bestv[r] = 3.4e38f; bestk[r] = 0; }

    float4 pc[4];
    float pt2 = 0.0f;
#pragma unroll
    for (int it = 0; it < 4; ++it) {
        int g = t + 512 * it;
        int c = g >> 5, dq = g & 31;
        int cc = kbeg + c; if (cc >= K) cc = K - 1;
        pc[it] = *(const float4*)(cb + (size_t)cc * DD + 4 * dq);
    }
    if (t < 64) { int cc = kbeg + t; if (cc >= K) cc = K - 1; pt2 = t2[cc]; }

    for (int k0 = kbeg; k0 < kend; k0 += 64) {
        __syncthreads();
#pragma unroll
        for (int it = 0; it < 4; ++it) {
            int g = t + 512 * it;
            int c = g >> 5, dq = g & 31;
            Cs[4*dq+0][c] = pc[it].x; Cs[4*dq+1][c] = pc[it].y;
            Cs[4*dq+2][c] = pc[it].z; Cs[4*dq+3][c] = pc[it].w;
        }
        if (t < 64) T2s[t] = pt2;
        __syncthreads();

        if (k0 + 64 < kend) {
            const int kn = k0 + 64;
#pragma unroll
            for (int it = 0; it < 4; ++it) {
                int g = t + 512 * it;
                int c = g >> 5, dq = g & 31;
                int cc = kn + c; if (cc >= K) cc = K - 1;
                pc[it] = *(const float4*)(cb + (size_t)cc * DD + 4 * dq);
            }
            if (t < 64) { int cc = kn + t; if (cc >= K) cc = K - 1; pt2 = t2[cc]; }
        }

        float s[4][2];
#pragma unroll
        for (int r = 0; r < 4; ++r) { s[r][0] = 0.0f; s[r][1] = 0.0f; }

#pragma unroll 8
        for (int d = 0; d < 128; ++d) {
            const float4 a4 = *(const float4*)&Ls[d][4 * tx];
            const float2 c2 = *(const float2*)&Cs[d][2 * ty];
            const float av[4] = {a4.x, a4.y, a4.z, a4.w};
#pragma unroll
            for (int r = 0; r < 4; ++r) {
                s[r][0] = fmaf(av[r], c2.x, s[r][0]);
                s[r][1] = fmaf(av[r], c2.y, s[r][1]);
            }
        }

#pragma unroll
        for (int r = 0; r < 4; ++r) {
            const float t1 = T1s[4 * tx + r];
#pragma unroll
            for (int j = 0; j < 2; ++j) {
                int kc = k0 + 2 * ty + j;
                float dist = (t1 + T2s[2 * ty + j]) - 2.0f * s[r][j];
                if (kc < K && dist < bestv[r]) { bestv[r] = dist; bestk[r] = kc; }
            }
        }
    }

#pragma unroll
    for (int off = 16; off <= 32; off <<= 1) {
#pragma unroll
        for (int r = 0; r < 4; ++r) {
            float vv = __shfl_xor(bestv[r], off);
            int kk = __shfl_xor(bestk[r], off);
            if (vv < bestv[r] || (vv == bestv[r] && kk < bestk[r])) {
                bestv[r] = vv; bestk[r] = kk;
            }
        }
    }
    if (lane < 16) {
#pragma unroll
        for (int r = 0; r < 4; ++r) {
            bwv[wave][4 * lane + r] = bestv[r];
            bwk[wave][4 * lane + r] = bestk[r];
        }
    }
    __syncthreads();
    if (t < 64) {
        float bv = bwv[0][t]; int bk = bwk[0][t];
#pragma unroll
        for (int w = 1; w < 8; ++w) {
            float v = bwv[w][t]; int k = bwk[w][t];
            if (v < bv || (v == bv && k < bk)) { bv = v; bk = k; }
        }
        if (r0 + t < rows_total) {
            size_t o = (size_t)blockIdx.y * rows_total + (r0 + t);
            pbv[o] = bv;
            pbk[o] = bk;
        }
    }
}

// combine K-split partials + write int indices AND float copy (fused old idx_out)
__global__ __launch_bounds__(256) void vq_combine(const float* __restrict__ pbv,
                                                  const int* __restrict__ pbk,
                                                  int S, int rows,
                                                  int* __restrict__ indices,
                                                  float* __restrict__ fidx,
                                                  double* __restrict__ acc) {
    int r = blockIdx.x * 256 + threadIdx.x;
    float bv = 3.4e38f; int bk = 0;
    if (r < rows) {
        for (int s = 0; s < S; ++s) {
            float v = pbv[(size_t)s * rows + r];
            int k = pbk[(size_t)s * rows + r];
            if (v < bv) { bv = v; bk = k; }
        }
        indices[r] = bk;
        fidx[r] = (float)bk;
    }
    __shared__ double red[256];
    red[threadIdx.x] = (r < rows) ? (double)bv : 0.0;
    __syncthreads();
    for (int s = 128; s > 0; s >>= 1) {
        if (threadIdx.x < s) red[threadIdx.x] += red[threadIdx.x + s];
        __syncthreads();
    }
    if (threadIdx.x == 0) atomicAdd(acc, red[0]);
}

// ---------------- Q gather ----------------
__global__ void q_gather(const int* __restrict__ idx, const float* __restrict__ cb,
                         float* __restrict__ Q, int count, int nlat) {
    int gid = blockIdx.x * 256 + threadIdx.x;
    if (gid >= count) return;
    int m = gid >> 11;            // / LAT (2048, verified)
    int j = gid & 2047;
    int code = idx[m * nlat + (j >> 7)];
    Q[gid] = cb[((size_t)code << 7) + (j & 127)];
}

__global__ void finalize(const double* __restrict__ acc, float* __restrict__ out,
                         double vq_den, double rec_den) {
    double vq = 1.25 * acc[0] / vq_den;
    double rl = acc[1] / rec_den;
    out[0] = (float)vq;
    out[1] = (float)rl;
    out[2] = (float)(rl + vq);
}

static inline int ceildiv(int a, int b) { return (a + b - 1) / b; }

// ---------------- launch ----------------
extern "C" void kernel_launch(void* const* d_in, const int* in_sizes, int n_in,
                              void* d_out, int out_size, void* d_ws, size_t ws_size,
                              hipStream_t stream) {
    const float* actions = (const float*)d_in[0];
    const float* e_w1 = (const float*)d_in[1];
    const float* e_b1 = (const float*)d_in[2];
    const float* e_w2 = (const float*)d_in[3];
    const float* e_b2 = (const float*)d_in[4];
    const float* e_w3 = (const float*)d_in[5];
    const float* e_b3 = (const float*)d_in[6];
    const float* cb   = (const float*)d_in[7];
    const float* d_w1 = (const float*)d_in[8];
    const float* d_b1 = (const float*)d_in[9];
    const float* d_w2 = (const float*)d_in[10];
    const float* d_b2 = (const float*)d_in[11];
    const float* d_w3 = (const float*)d_in[12];
    const float* d_b3 = (const float*)d_in[13];
    float* out = (float*)d_out;

    const int FLAT = in_sizes[13];
    const int B    = in_sizes[0] / FLAT;
    const int HID  = in_sizes[2];
    const int LAT  = in_sizes[6];
    const int K    = in_sizes[7] / DD;
    const int NL   = LAT / DD;

    const bool g88 = (K % VQG_CPP == 0);
    const int S = 1;
    const int Kc = K;

    int CHUNK = B;                                // full-batch; halve only if ws too small
    auto need = [&](int ch) -> size_t {
        return (size_t)ch * HID * 4 * 2 + (size_t)ch * LAT * 4 * 2
             + (size_t)ch * HID * 4 * 2 + (size_t)ch * FLAT * 4
             + (size_t)K * 4 + (size_t)K * DD * 4 + 64 + (size_t)B * NL * 4
             + (size_t)ch * NL * S * 8;
    };
    while (CHUNK > 16 && need(CHUNK) > ws_size) CHUNK >>= 1;
    if (need(CHUNK) > ws_size) {
        plant_diag<<<1, 64, 0, stream>>>(2222.0f, out);
        return;
    }
    const int NCHUNK = ceildiv(B, CHUNK);

    char* ws = (char*)d_ws;
    size_t off = 0;
    float* h1c  = (float*)(ws + off); off += (size_t)CHUNK * HID * 4;
    float* h2c  = (float*)(ws + off); off += (size_t)CHUNK * HID * 4;
    float* latc = (float*)(ws + off); off += (size_t)CHUNK * LAT * 4;
    float* Qc   = (float*)(ws + off); off += (size_t)CHUNK * LAT * 4;
    float* g1c  = (float*)(ws + off); off += (size_t)CHUNK * HID * 4;
    float* g2c  = (float*)(ws + off); off += (size_t)CHUNK * HID * 4;
    float* recc = (float*)(ws + off); off += (size_t)CHUNK * FLAT * 4;   // unused (fused)
    float* t2   = (float*)(ws + off); off += (size_t)K * 4;
    float* cbP  = (float*)(ws + off); off += (size_t)K * DD * 4;
    double* acc = (double*)(ws + off); off += 64;
    int*   idx  = (int*)(ws + off);   off += (size_t)B * NL * 4;
    float* pbv  = (float*)(ws + off); off += (size_t)CHUNK * NL * S * 4;
    int*   pbk  = (int*)(ws + off);
    (void)recc;

    zero_acc<<<1, 64, 0, stream>>>(acc);
    code_t2<<<ceildiv(K, 256), 256, 0, stream>>>(cb, t2, K);
    if (g88) {
        cb_pack<<<ceildiv(K * DD, 256), 256, 0, stream>>>(cb, cbP, K * DD);
    }

    for (int c = 0; c < NCHUNK; ++c) {
        const int r0 = c * CHUNK;
        const int cbR = (B - r0 < CHUNK) ? (B - r0) : CHUNK;
        const float* act_c = actions + (size_t)r0 * FLAT;
        int* idx_c = idx + (size_t)r0 * NL;
        const int rows = cbR * NL;

        // encoder: 128x64-tile LDS-staged exact-chain GEMMs (round-10 proven)
        gemm_db<true><<<dim3(ceildiv(HID, 64), ceildiv(cbR, 128)), 256, 0, stream>>>(
            act_c, e_w1, e_b1, h1c, cbR, HID, FLAT);
        gemm_db<true><<<dim3(ceildiv(HID, 64), ceildiv(cbR, 128)), 256, 0, stream>>>(
            h1c, e_w2, e_b2, h2c, cbR, HID, HID);
        gemm_db<false><<<dim3(ceildiv(LAT, 64), ceildiv(cbR, 128)), 256, 0, stream>>>(
            h2c, e_w3, e_b3, latc, cbR, LAT, HID);

        // VQ: packed-pair codebook + v_pk_fma_f32 kernel (bit-identical) + fused combine
        if (g88) {
            vq_g88p<<<ceildiv(rows, VQG_ROWS), 512, 0, stream>>>(
                latc, cbP, t2, pbv, pbk, K, rows);
        } else {
            vq_np4<<<dim3(ceildiv(rows, 64), S), 512, 0, stream>>>(
                latc, cb, t2, pbv, pbk, K, Kc, rows);
        }
        vq_combine<<<ceildiv(rows, 256), 256, 0, stream>>>(
            pbv, pbk, S, rows, idx_c,
            out + (size_t)B * FLAT + (size_t)r0 * NL, acc);

        // decoder (d3 fused with recon write + loss)
        q_gather<<<ceildiv(cbR * LAT, 256), 256, 0, stream>>>(idx_c, cb, Qc, cbR * LAT, NL);
        gemm_db<true><<<dim3(ceildiv(HID, 64), ceildiv(cbR, 128)), 256, 0, stream>>>(
            Qc, d_w1, d_b1, g1c, cbR, HID, LAT);
        gemm_db<true><<<dim3(ceildiv(HID, 64), ceildiv(cbR, 128)), 256, 0, stream>>>(
            g1c, d_w2, d_b2, g2c, cbR, HID, HID);
        gemm64r<<<dim3(ceildiv(FLAT, 64), ceildiv(cbR, 64)), 256, 0, stream>>>(
            g2c, d_w3, d_b3, act_c, out + (size_t)r0 * FLAT, acc, cbR, FLAT, HID);
    }

    finalize<<<1, 1, 0, stream>>>(acc, out + (size_t)B * FLAT + (size_t)B * NL,
                                  (double)B * NL * DD, (double)B * FLAT);
}